// Round 2
// baseline (1109.734 us; speedup 1.0000x reference)
//
#include <hip/hip_runtime.h>

#define NN 200000
#define EE 400000
#define GG 4096

// ws layout (float offsets)
#define AGG_OFF 0
#define H1_OFF  (NN * 64)            // 12,800,000
#define SE_OFF  (H1_OFF + NN * 64)   // 25,600,000 (2*GG ints)

// ---------------- segment boundaries from sorted batch ----------------
__global__ void bounds_kernel(const int* __restrict__ batch, int* __restrict__ se) {
    int n = blockIdx.x * blockDim.x + threadIdx.x;
    if (n >= NN) return;
    int b = batch[n];
    if (n == 0 || batch[n - 1] != b) se[b] = n;                 // start
    if (n == NN - 1 || batch[n + 1] != b) se[GG + b] = n + 1;   // end
}

// ---------------- edge pass: m = relu(x[src] + ea@W + b); atomic scatter to agg[dst]
// one wave per edge; lane = output channel
__global__ __launch_bounds__(256) void edge_pass(const float* __restrict__ xin,
                                                 const int* __restrict__ ei,
                                                 const float* __restrict__ ea,
                                                 const float* __restrict__ ew,
                                                 const float* __restrict__ eb,
                                                 float* __restrict__ agg) {
    const int lane = threadIdx.x & 63;
    float Wr[16];
#pragma unroll
    for (int k = 0; k < 16; k++) Wr[k] = ew[k * 64 + lane];   // ew: (16,64)
    const float br = eb[lane];

    int w = blockIdx.x * 4 + (threadIdx.x >> 6);
    int nw = gridDim.x * 4;
    const float4* ea4 = (const float4*)ea;

    for (int e = w; e < EE; e += nw) {
        int s = __builtin_amdgcn_readfirstlane(ei[e]);
        int d = __builtin_amdgcn_readfirstlane(ei[EE + e]);
        float4 p0 = ea4[(size_t)e * 4 + 0];
        float4 p1 = ea4[(size_t)e * 4 + 1];
        float4 p2 = ea4[(size_t)e * 4 + 2];
        float4 p3 = ea4[(size_t)e * 4 + 3];
        float ev[16] = { p0.x, p0.y, p0.z, p0.w, p1.x, p1.y, p1.z, p1.w,
                         p2.x, p2.y, p2.z, p2.w, p3.x, p3.y, p3.z, p3.w };
        float acc = br;
#pragma unroll
        for (int k = 0; k < 16; k++) acc += ev[k] * Wr[k];
        float xv = xin[(size_t)s * 64 + lane];
        float m = fmaxf(acc + xv, 0.0f);
        atomicAdd(agg + (size_t)d * 64 + lane, m);
    }
}

// ---------------- node MLP layer 1: h1 = relu( relu((x+agg)@W1+b1) @ W2 + b2 )
__global__ __launch_bounds__(256, 1) void node1_kernel(const float* __restrict__ x,
                                                       const float* __restrict__ agg,
                                                       const float* __restrict__ W1,
                                                       const float* __restrict__ B1,
                                                       const float* __restrict__ W2,
                                                       const float* __restrict__ B2,
                                                       float* __restrict__ h1) {
    int n = blockIdx.x * 256 + threadIdx.x;
    if (n >= NN) return;

    float hin[64];
    const float4* x4 = (const float4*)(x + (size_t)n * 64);
    const float4* a4 = (const float4*)(agg + (size_t)n * 64);
#pragma unroll
    for (int q = 0; q < 16; q++) {
        float4 a = x4[q], b = a4[q];
        hin[4*q+0] = a.x + b.x; hin[4*q+1] = a.y + b.y;
        hin[4*q+2] = a.z + b.z; hin[4*q+3] = a.w + b.w;
    }

    float out[64];
#pragma unroll
    for (int c = 0; c < 64; c++) out[c] = B2[c];

    for (int jc = 0; jc < 64; jc += 16) {  // 4 iterations (not unrolled)
        float t[16];
#pragma unroll
        for (int j = 0; j < 16; j++) t[j] = B1[jc + j];
#pragma unroll
        for (int k = 0; k < 64; k++) {
            float hv = hin[k];
#pragma unroll
            for (int j = 0; j < 16; j++) t[j] += hv * W1[k * 64 + jc + j];
        }
#pragma unroll
        for (int j = 0; j < 16; j++) t[j] = fmaxf(t[j], 0.0f);
#pragma unroll
        for (int j = 0; j < 16; j++) {
            float tv = t[j];
#pragma unroll
            for (int c = 0; c < 64; c++) out[c] += tv * W2[(jc + j) * 64 + c];
        }
    }

    float4* o4 = (float4*)(h1 + (size_t)n * 64);
#pragma unroll
    for (int q = 0; q < 16; q++) {
        float4 v;
        v.x = fmaxf(out[4*q+0], 0.0f);
        v.y = fmaxf(out[4*q+1], 0.0f);
        v.z = fmaxf(out[4*q+2], 0.0f);
        v.w = fmaxf(out[4*q+3], 0.0f);
        o4[q] = v;
    }
}

// ---------------- node MLP layer 2 (no outer relu), written IN PLACE:
//   hout[0:64) -> agg[n], hout[64:128) -> h1[n]
__global__ __launch_bounds__(256, 1) void node2_kernel(float* __restrict__ h1,
                                                       float* __restrict__ agg,
                                                       const float* __restrict__ W1,
                                                       const float* __restrict__ B1,
                                                       const float* __restrict__ W2,
                                                       const float* __restrict__ B2) {
    int n = blockIdx.x * 256 + threadIdx.x;
    if (n >= NN) return;

    float hin[64];
    const float4* h4 = (const float4*)(h1 + (size_t)n * 64);
    const float4* a4 = (const float4*)(agg + (size_t)n * 64);
#pragma unroll
    for (int q = 0; q < 16; q++) {
        float4 a = h4[q], b = a4[q];
        hin[4*q+0] = a.x + b.x; hin[4*q+1] = a.y + b.y;
        hin[4*q+2] = a.z + b.z; hin[4*q+3] = a.w + b.w;
    }

    float out[128];
#pragma unroll
    for (int c = 0; c < 128; c++) out[c] = B2[c];

    for (int jc = 0; jc < 128; jc += 8) {  // 16 iterations (not unrolled)
        float t[8];
#pragma unroll
        for (int j = 0; j < 8; j++) t[j] = B1[jc + j];
#pragma unroll
        for (int k = 0; k < 64; k++) {
            float hv = hin[k];
#pragma unroll
            for (int j = 0; j < 8; j++) t[j] += hv * W1[k * 128 + jc + j];
        }
#pragma unroll
        for (int j = 0; j < 8; j++) t[j] = fmaxf(t[j], 0.0f);
#pragma unroll
        for (int j = 0; j < 8; j++) {
            float tv = t[j];
#pragma unroll
            for (int c = 0; c < 128; c++) out[c] += tv * W2[(jc + j) * 128 + c];
        }
    }

    float4* oa = (float4*)(agg + (size_t)n * 64);
    float4* oh = (float4*)(h1 + (size_t)n * 64);
#pragma unroll
    for (int q = 0; q < 16; q++) {
        float4 v;
        v.x = out[4*q+0]; v.y = out[4*q+1]; v.z = out[4*q+2]; v.w = out[4*q+3];
        oa[q] = v;
        float4 w;
        w.x = out[64+4*q+0]; w.y = out[64+4*q+1]; w.z = out[64+4*q+2]; w.w = out[64+4*q+3];
        oh[q] = w;
    }
}

// ---------------- head: mean-pool (via segment bounds) + 5-layer MLP ----------------
__global__ __launch_bounds__(128) void head_kernel(const float* __restrict__ hlo,  // hout[0:64)
                                                   const float* __restrict__ hhi,  // hout[64:128)
                                                   const int* __restrict__ se,
                                                   const float* __restrict__ usr,
                                                   const float* __restrict__ h1w, const float* __restrict__ h1b,
                                                   const float* __restrict__ h2w, const float* __restrict__ h2b,
                                                   const float* __restrict__ h3w, const float* __restrict__ h3b,
                                                   const float* __restrict__ h4w, const float* __restrict__ h4b,
                                                   const float* __restrict__ h5w, const float* __restrict__ h5b,
                                                   float* __restrict__ out) {
    int g = blockIdx.x;
    int c = threadIdx.x;
    __shared__ float z0[140];
    __shared__ float z1[128];
    __shared__ float z2[64];
    __shared__ float z3[32];
    __shared__ float z4[16];

    int s = se[g], e = se[GG + g];
    float sum = 0.0f;
    if (c < 64) {
        for (int n = s; n < e; n++) sum += hlo[(size_t)n * 64 + c];
    } else {
        for (int n = s; n < e; n++) sum += hhi[(size_t)n * 64 + (c - 64)];
    }
    float cnt = fmaxf((float)(e - s), 1.0f);
    z0[c] = sum / cnt;
    if (c < 12) z0[128 + c] = usr[g * 12 + c];
    __syncthreads();

    // L1: 140 -> 128
    {
        float acc = h1b[c];
        for (int k = 0; k < 140; k++) acc += z0[k] * h1w[k * 128 + c];
        z1[c] = fmaxf(acc, 0.0f);
    }
    __syncthreads();
    // L2: 128 -> 64
    if (c < 64) {
        float acc = h2b[c];
        for (int k = 0; k < 128; k++) acc += z1[k] * h2w[k * 64 + c];
        z2[c] = fmaxf(acc, 0.0f);
    }
    __syncthreads();
    // L3: 64 -> 32
    if (c < 32) {
        float acc = h3b[c];
        for (int k = 0; k < 64; k++) acc += z2[k] * h3w[k * 32 + c];
        z3[c] = fmaxf(acc, 0.0f);
    }
    __syncthreads();
    // L4: 32 -> 16
    if (c < 16) {
        float acc = h4b[c];
        for (int k = 0; k < 32; k++) acc += z3[k] * h4w[k * 16 + c];
        z4[c] = fmaxf(acc, 0.0f);
    }
    __syncthreads();
    // L5: 16 -> 1
    if (c == 0) {
        float acc = h5b[0];
        for (int k = 0; k < 16; k++) acc += z4[k] * h5w[k];
        out[g] = acc;
    }
}

extern "C" void kernel_launch(void* const* d_in, const int* in_sizes, int n_in,
                              void* d_out, int out_size, void* d_ws, size_t ws_size,
                              hipStream_t stream) {
    const float* x    = (const float*)d_in[0];
    const int*   ei   = (const int*)d_in[1];
    const float* ea   = (const float*)d_in[2];
    const int*   batch= (const int*)d_in[3];
    const float* usr  = (const float*)d_in[4];
    const float* e1w  = (const float*)d_in[5],  *e1b  = (const float*)d_in[6];
    const float* n1w1 = (const float*)d_in[7],  *n1b1 = (const float*)d_in[8];
    const float* n1w2 = (const float*)d_in[9],  *n1b2 = (const float*)d_in[10];
    const float* e2w  = (const float*)d_in[11], *e2b  = (const float*)d_in[12];
    const float* n2w1 = (const float*)d_in[13], *n2b1 = (const float*)d_in[14];
    const float* n2w2 = (const float*)d_in[15], *n2b2 = (const float*)d_in[16];
    const float* h1w  = (const float*)d_in[17], *h1b  = (const float*)d_in[18];
    const float* h2w  = (const float*)d_in[19], *h2b  = (const float*)d_in[20];
    const float* h3w  = (const float*)d_in[21], *h3b  = (const float*)d_in[22];
    const float* h4w  = (const float*)d_in[23], *h4b  = (const float*)d_in[24];
    const float* h5w  = (const float*)d_in[25], *h5b  = (const float*)d_in[26];

    float* w   = (float*)d_ws;
    float* agg = w + AGG_OFF;
    float* h1  = w + H1_OFF;
    int*   se  = (int*)(w + SE_OFF);

    hipMemsetAsync(agg, 0, (size_t)NN * 64 * sizeof(float), stream);
    hipMemsetAsync(se, 0, (size_t)GG * 2 * sizeof(int), stream);

    bounds_kernel<<<(NN + 255) / 256, 256, 0, stream>>>(batch, se);

    edge_pass<<<4096, 256, 0, stream>>>(x, ei, ea, e1w, e1b, agg);
    node1_kernel<<<(NN + 255) / 256, 256, 0, stream>>>(x, agg, n1w1, n1b1, n1w2, n1b2, h1);

    hipMemsetAsync(agg, 0, (size_t)NN * 64 * sizeof(float), stream);
    edge_pass<<<4096, 256, 0, stream>>>(h1, ei, ea, e2w, e2b, agg);
    node2_kernel<<<(NN + 255) / 256, 256, 0, stream>>>(h1, agg, n2w1, n2b1, n2w2, n2b2);

    head_kernel<<<GG, 128, 0, stream>>>(agg, h1, se, usr,
                                        h1w, h1b, h2w, h2b, h3w, h3b, h4w, h4b, h5w, h5b,
                                        (float*)d_out);
}